// Round 14
// baseline (114.360 us; speedup 1.0000x reference)
//
#include <hip/hip_runtime.h>
#include <math.h>

#define VOCAB 50257
#define BSZ   64
#define BEAM  8
#define NG    4     // NUM_GROUPS
#define MB    2     // beams per group
#define KC    2     // candidates per group
#define TLEN  128
#define NGRAM 2
#define SEG    64
#define SEGLEN 786               // 64*786 = 50304 >= 50257
#define ROWS  (BSZ * BEAM)       // 512
#define MAXK  8                  // max slices per row
#define CAPQ  256                // candidate capacity per slice

__device__ __forceinline__ bool better(float v1, int i1, float v2, int i2) {
    return (v1 > v2) || (v1 == v2 && i1 < i2);
}

struct Top2 { float v1, v2; int i1, i2; };

__device__ __forceinline__ void t2_init(Top2& t) {
    t.v1 = -INFINITY; t.v2 = -INFINITY; t.i1 = 0x7FFFFFFF; t.i2 = 0x7FFFFFFF;
}

__device__ __forceinline__ void t2_push(Top2& t, float v, int i) {
    if (better(v, i, t.v2, t.i2)) {
        if (better(v, i, t.v1, t.i1)) { t.v2 = t.v1; t.i2 = t.i1; t.v1 = v; t.i1 = i; }
        else                          { t.v2 = v;    t.i2 = i; }
    }
}

__device__ __forceinline__ void t2_merge(Top2& a, const Top2& b) {
    if (better(b.v1, b.i1, a.v1, a.i1)) {
        float nv2; int ni2;
        if (better(a.v1, a.i1, b.v2, b.i2)) { nv2 = a.v1; ni2 = a.i1; }
        else                                { nv2 = b.v2; ni2 = b.i2; }
        a.v1 = b.v1; a.i1 = b.i1; a.v2 = nv2; a.i2 = ni2;
    } else {
        if (better(b.v1, b.i1, a.v2, a.i2)) { a.v2 = b.v1; a.i2 = b.i1; }
    }
}

__device__ __forceinline__ float max4(float4 v) {
    return fmaxf(fmaxf(v.x, v.y), fmaxf(v.z, v.w));
}

// ---- per-batch 4-group chain + outputs; one wave; register-resident. -------
// ws data read through VOLATILE (cross-block producer; pointers non-restrict).
// For batches whose rows are all invalid this touches no ws memory.
__device__ void finalize_batch(
    int bb, int lane, int k,
    const float* scores, const float* overlap, const int* obi,
    const int* lastn, const int* mask, int step,
    const volatile int* wscnt, const volatile float* wscv,
    const volatile int* wsci, float* out)
{
    const int ob = obi[bb];
    float selv[NG][KC]; int seli[NG][KC]; int selm[NG][KC];

    #pragma unroll
    for (int g = 0; g < NG; ++g) {
        Top2 t; t2_init(t);
        #pragma unroll
        for (int m = 0; m < MB; ++m) {
            const int rr  = bb * BEAM + m * NG + g;
            const int mka = mask[rr * NGRAM], mkb = mask[rr * NGRAM + 1];
            const float sc = scores[(size_t)rr * TLEN + (step - 1)];
            if (mka + mkb == NGRAM) {
                for (int qq = 0; qq < k; ++qq) {
                    const int slot = rr * MAXK + qq;
                    const int n = wscnt[slot];              // volatile load
                    for (int c = lane; c < n; c += 64) {
                        const float v   = wscv[(size_t)slot * CAPQ + c];
                        const int   idx = wsci[(size_t)slot * CAPQ + c];
                        float dv = 0.0f;
                        #pragma unroll
                        for (int j = 0; j < NG - 1; ++j) {
                            if (j < g) {    // g,j literals: static reg indexing
                                const float pen =
                                    1.0f + overlap[((size_t)ob * NG + g) * NG + j];
                                if (seli[j][0] == idx) dv += pen;
                                if (seli[j][1] == idx) dv += pen;
                            }
                        }
                        t2_push(t, v - 0.5f * dv + sc, m * VOCAB + idx);
                    }
                }
            } else if (lane < KC) {
                // invalid row: constant sc -> best two flat idx m*V, m*V+1
                t2_push(t, sc, m * VOCAB + lane);
            }
        }
        #pragma unroll
        for (int off = 32; off > 0; off >>= 1) {
            Top2 o;
            o.v1 = __shfl_down(t.v1, off); o.i1 = __shfl_down(t.i1, off);
            o.v2 = __shfl_down(t.v2, off); o.i2 = __shfl_down(t.i2, off);
            t2_merge(t, o);
        }
        t.v1 = __shfl(t.v1, 0); t.i1 = __shfl(t.i1, 0);
        t.v2 = __shfl(t.v2, 0); t.i2 = __shfl(t.i2, 0);
        selv[g][0] = t.v1; seli[g][0] = t.i1 % VOCAB; selm[g][0] = t.i1 / VOCAB;
        selv[g][1] = t.v2; seli[g][1] = t.i2 % VOCAB; selm[g][1] = t.i2 / VOCAB;
    }

    // outputs: scores[0,512) indices[512,1024) beams[1024,1536) overlap[1536,2560)
    #pragma unroll
    for (int g = 0; g < NG; ++g) {
        #pragma unroll
        for (int m = 0; m < MB; ++m) {
            const int i = m * NG + g;
            if (lane == 8 + i) {
                out[(size_t)bb * BEAM + i]        = selv[g][m];
                out[512 + (size_t)bb * BEAM + i]  = (float)seli[g][m];
                out[1024 + (size_t)bb * BEAM + i] = (float)(selm[g][m] * NG + g);
            }
        }
    }
    #pragma unroll
    for (int q = 0; q < NG * NG; ++q) {
        if (lane == 24 + q) {
            const int g1 = q / NG, g2 = q % NG;
            int ov = 0;
            #pragma unroll
            for (int m = 0; m < MB; ++m) {
                const int i1 = m * NG + g1, i2 = m * NG + g2;
                const int p1a = lastn[(size_t)bb * BEAM + i1];
                const int p2a = lastn[(size_t)bb * BEAM + i2];
                const int* mk1 = mask + ((size_t)bb * BEAM + i1) * NGRAM;
                const int* mk2 = mask + ((size_t)bb * BEAM + i2) * NGRAM;
                const bool e0 = (p1a == p2a) && (mk1[0] != 0) && (mk2[0] != 0);
                const bool e1 = (seli[g1][m] == seli[g2][m])
                                && (mk1[1] != 0) && (mk2[1] != 0);
                ov += (e0 && e1) ? 1 : 0;
            }
            out[1536 + (size_t)ob * (NG * NG) + q] =
                (overlap[(size_t)ob * (NG * NG) + q] + (float)ov) * 0.5f;
        }
    }
}

// ---- single kernel: worklist scan -> per-batch last-arriver finalize -------
// done[] is memset to 0 each call (graph node) -> clean rendezvous, no spin,
// no cross-call state. ws pointers deliberately NON-const, NON-restrict so
// the compiler cannot hoist/cache reads of data written by other blocks.
__global__ __launch_bounds__(1024, 8) void dbs_all(
    const float* __restrict__ lprobs, const float* __restrict__ scores,
    const float* __restrict__ overlap, const int* __restrict__ obi,
    const int* __restrict__ lastn, const int* __restrict__ mask,
    const int* __restrict__ stepp,
    int* wscnt, float* wscv, int* wsci, int* done,
    float* out)
{
    const int tid  = threadIdx.x;
    const int w    = tid >> 6, lane = tid & 63;
    const int step = stepp[0];

    __shared__ unsigned long long s_bits[8];
    __shared__ float s_max[16];
    __shared__ float s_tau;
    __shared__ int   s_cnt;
    __shared__ int   s_fin;
    __shared__ float s_cv[CAPQ];
    __shared__ int   s_ci[CAPQ];

    // ---- classify all 512 rows -> validity bitmask (deterministic) ----
    bool validp = false;
    if (tid < ROWS) {
        const int2 mk = ((const int2*)mask)[tid];
        validp = (mk.x + mk.y) == NGRAM;
    }
    const unsigned long long bm = __ballot(validp);
    if (w < 8 && lane == 0) s_bits[w] = bm;
    if (tid == 0) s_cnt = 0;
    __syncthreads();

    int nv = 0;
    #pragma unroll
    for (int i = 0; i < 8; ++i) nv += __popcll(s_bits[i]);
    int k = 1;
    if (nv > 0) {
        const int q = ROWS / nv;
        k = (q >= 8) ? 8 : (q >= 4) ? 4 : (q >= 2) ? 2 : 1;
    }

    const int b = blockIdx.x;
    if (b >= nv * k) {
        // non-working block; only possible owner of empty-duty here is b==0
        // when nv==0 (then ALL batches are empty -> analytic everywhere).
        if (b == 0) {
            for (int bb = w; bb < BSZ; bb += 16)
                finalize_batch(bb, lane, k, scores, overlap, obi, lastn, mask,
                               step, (const volatile int*)wscnt,
                               (const volatile float*)wscv,
                               (const volatile int*)wsci, out);
        }
        return;
    }

    // ---- map b -> (r = vidx-th valid row, slice) ----
    const int vidx  = b / k;
    const int slice = b - vidx * k;
    int r = 0, cnt = 0;
    for (int i = 0; i < 8; ++i) {
        const unsigned long long x = s_bits[i];
        const int c = __popcll(x);
        if (cnt + c > vidx) {
            unsigned long long y = x;
            for (int need = vidx - cnt; need > 0; --need) y &= y - 1;
            r = i * 64 + (__ffsll(y) - 1);
            break;
        }
        cnt += c;
    }

    const size_t rowoff = (size_t)r * VOCAB;
    const float* row = lprobs + rowoff;
    const int segs = SEG / k;
    const int A    = slice * segs * SEGLEN;
    const int Bv   = min(A + segs * SEGLEN, VOCAB);
    const int L    = Bv - A;
    const int subL = (L + 15) >> 4;     // 16 sub-segments, all nonempty

    const int start = A + w * subL;
    const int end   = min(start + subL, Bv);

    // ---- pass 1: sub-segment max ----
    float m = -INFINITY;
    const int mis = (int)((rowoff + start) & 3);
    int pre = (4 - mis) & 3;
    if (pre > end - start) pre = end - start;
    if (lane < pre) m = row[start + lane];
    const int vstart = start + pre;
    const int n4 = (end - vstart) >> 2;
    const float4* vrow = (const float4*)(row + vstart);
    const int nc = n4 >> 6;

    float a0 = -INFINITY, a1 = -INFINITY;
    for (int c = 0; c < nc; ++c) {
        const float4 v = vrow[c * 64 + lane];
        a0 = fmaxf(fmaxf(a0, fmaxf(v.x, v.y)), fmaxf(v.z, v.w));
    }
    {
        const int jj = nc * 64 + lane;
        if (jj < n4) {
            const float4 v = vrow[jj];
            a1 = fmaxf(fmaxf(a1, fmaxf(v.x, v.y)), fmaxf(v.z, v.w));
        }
        const int tstart = vstart + 4 * n4;
        if (tstart + lane < end) a1 = fmaxf(a1, row[tstart + lane]);
    }
    m = fmaxf(m, fmaxf(a0, a1));
    #pragma unroll
    for (int off = 32; off > 0; off >>= 1) m = fmaxf(m, __shfl_xor(m, off));
    if (lane == 0) s_max[w] = m;
    __syncthreads();

    // ---- tau = 8th largest (lex) of the 16 sub-maxima ----
    if (w == 0) {
        const float mym = (lane < 16) ? s_max[lane] : -INFINITY;
        int rank = 0;
        #pragma unroll
        for (int i = 0; i < 16; ++i) {
            const float om = __shfl(mym, i);
            rank += better(om, i, mym, lane) ? 1 : 0;
        }
        if (lane < 16 && rank == 7) s_tau = mym;
    }
    __syncthreads();
    const float tau = s_tau;

    // ---- pass 2: rescan only sub-segments with max >= tau (exactly 8) ----
    if (s_max[w] >= tau) {
        if (lane < pre) {
            const float v = row[start + lane];
            if (v >= tau) {
                const int p = atomicAdd(&s_cnt, 1);
                if (p < CAPQ) { s_cv[p] = v; s_ci[p] = start + lane; }
            }
        }
        for (int jj0 = 0; jj0 < n4; jj0 += 64) {
            const int jj = jj0 + lane;
            if (jj < n4) {
                const float4 v = vrow[jj];
                if (max4(v) >= tau) {
                    const int base = vstart + 4 * jj;
                    if (v.x >= tau) { const int p = atomicAdd(&s_cnt,1); if (p<CAPQ){s_cv[p]=v.x; s_ci[p]=base;} }
                    if (v.y >= tau) { const int p = atomicAdd(&s_cnt,1); if (p<CAPQ){s_cv[p]=v.y; s_ci[p]=base+1;} }
                    if (v.z >= tau) { const int p = atomicAdd(&s_cnt,1); if (p<CAPQ){s_cv[p]=v.z; s_ci[p]=base+2;} }
                    if (v.w >= tau) { const int p = atomicAdd(&s_cnt,1); if (p<CAPQ){s_cv[p]=v.w; s_ci[p]=base+3;} }
                }
            }
        }
        const int tstart = vstart + 4 * n4;
        if (tstart + lane < end) {
            const float v = row[tstart + lane];
            if (v >= tau) {
                const int p = atomicAdd(&s_cnt, 1);
                if (p < CAPQ) { s_cv[p] = v; s_ci[p] = tstart + lane; }
            }
        }
    }
    __syncthreads();

    // ---- emit candidates to global ws ----
    const int ccnt = min(s_cnt, CAPQ);
    const int slot = r * MAXK + slice;
    if (tid == 0) wscnt[slot] = ccnt;
    for (int c = tid; c < ccnt; c += 1024) {
        wscv[(size_t)slot * CAPQ + c] = s_cv[c];
        wsci[(size_t)slot * CAPQ + c] = s_ci[c];
    }

    // ---- rendezvous: publish, then last arriver of the batch finalizes ----
    const int myb  = r >> 3;
    const int nvb  = __popcll((s_bits[myb >> 3] >> ((myb & 7) * 8)) & 0xFFull);
    const int target = nvb * k;

    __threadfence();                      // release all emits (all threads)
    __syncthreads();
    if (tid == 0) {
        const int old = __hip_atomic_fetch_add(&done[myb], 1,
                            __ATOMIC_ACQ_REL, __HIP_MEMORY_SCOPE_AGENT);
        s_fin = (old == target - 1) ? 1 : 0;
    }
    __syncthreads();

    // block 0 spare waves: finalize batches with zero valid rows (analytic)
    if (b == 0 && w > 0) {
        for (int bb = w - 1; bb < BSZ; bb += 15) {
            const int nvb2 = __popcll((s_bits[bb >> 3] >> ((bb & 7) * 8)) & 0xFFull);
            if (nvb2 == 0)
                finalize_batch(bb, lane, k, scores, overlap, obi, lastn, mask,
                               step, (const volatile int*)wscnt,
                               (const volatile float*)wscv,
                               (const volatile int*)wsci, out);
        }
    }

    if (s_fin && w == 0) {
        __threadfence();                  // acquire side
        finalize_batch(myb, lane, k, scores, overlap, obi, lastn, mask, step,
                       (const volatile int*)wscnt, (const volatile float*)wscv,
                       (const volatile int*)wsci, out);
    }
}

extern "C" void kernel_launch(void* const* d_in, const int* in_sizes, int n_in,
                              void* d_out, int out_size, void* d_ws, size_t ws_size,
                              hipStream_t stream) {
    const float* lprobs  = (const float*)d_in[0];
    const float* scores  = (const float*)d_in[1];
    const float* overlap = (const float*)d_in[2];
    const int*   obi     = (const int*)d_in[3];
    const int*   lastn   = (const int*)d_in[4];
    const int*   mask    = (const int*)d_in[5];
    const int*   stepp   = (const int*)d_in[6];
    float*       out     = (float*)d_out;

    // ws: wscnt (512*MAXK i32) | wscv | wsci | done (64 i32)
    int*   wscnt = (int*)d_ws;
    float* wscv  = (float*)((char*)d_ws + (size_t)ROWS * MAXK * 4);
    int*   wsci  = (int*)((char*)d_ws + (size_t)ROWS * MAXK * 4
                          + (size_t)ROWS * MAXK * CAPQ * 4);
    int*   done  = (int*)((char*)d_ws + (size_t)ROWS * MAXK * 4
                          + (size_t)ROWS * MAXK * CAPQ * 8);

    hipMemsetAsync(done, 0, BSZ * sizeof(int), stream);   // clean rendezvous
    dbs_all<<<ROWS, 1024, 0, stream>>>(lprobs, scores, overlap, obi, lastn,
                                       mask, stepp, wscnt, wscv, wsci, done, out);
}

// Round 15
// 25.610 us; speedup vs baseline: 4.4655x; 4.4655x over previous
//
#include <hip/hip_runtime.h>
#include <math.h>

#define VOCAB 50257
#define BSZ   64
#define BEAM  8
#define NG    4     // NUM_GROUPS
#define MB    2     // beams per group
#define KC    2     // candidates per group
#define TLEN  128
#define NGRAM 2
#define SEG    64
#define SEGLEN 786               // 64*786 = 50304 >= 50257
#define ROWS  (BSZ * BEAM)       // 512
#define MAXK  8                  // max slices per row
#define CAPQ  256                // candidate capacity per slice

__device__ __forceinline__ bool better(float v1, int i1, float v2, int i2) {
    return (v1 > v2) || (v1 == v2 && i1 < i2);
}

struct Top2 { float v1, v2; int i1, i2; };

__device__ __forceinline__ void t2_init(Top2& t) {
    t.v1 = -INFINITY; t.v2 = -INFINITY; t.i1 = 0x7FFFFFFF; t.i2 = 0x7FFFFFFF;
}

__device__ __forceinline__ void t2_push(Top2& t, float v, int i) {
    if (better(v, i, t.v2, t.i2)) {
        if (better(v, i, t.v1, t.i1)) { t.v2 = t.v1; t.i2 = t.i1; t.v1 = v; t.i1 = i; }
        else                          { t.v2 = v;    t.i2 = i; }
    }
}

__device__ __forceinline__ void t2_merge(Top2& a, const Top2& b) {
    if (better(b.v1, b.i1, a.v1, a.i1)) {
        float nv2; int ni2;
        if (better(a.v1, a.i1, b.v2, b.i2)) { nv2 = a.v1; ni2 = a.i1; }
        else                                { nv2 = b.v2; ni2 = b.i2; }
        a.v1 = b.v1; a.i1 = b.i1; a.v2 = nv2; a.i2 = ni2;
    } else {
        if (better(b.v1, b.i1, a.v2, a.i2)) { a.v2 = b.v1; a.i2 = b.i1; }
    }
}

__device__ __forceinline__ float max4(float4 v) {
    return fmaxf(fmaxf(v.x, v.y), fmaxf(v.z, v.w));
}

// ---- K1: adaptive worklist scan; block = (valid-row ordinal, slice) --------
// Every block builds the same validity bitmask from mask (deterministic),
// derives k = slices/row (pow2 <= 512/nvalid, capped 8), so the nv*k working
// blocks are the FIRST block IDs -> round-robin over CUs -> balanced HBM pull.
__global__ __launch_bounds__(1024, 8) void dbs_candidates(
    const float* __restrict__ lprobs,   // (512, 50257)
    const int*   __restrict__ mask,     // (512, 2)
    int*   __restrict__ meta,           // [0] = k
    int*   __restrict__ wscnt,          // (512*MAXK,)
    float* __restrict__ wscv,           // (512*MAXK, CAPQ)
    int*   __restrict__ wsci)           // (512*MAXK, CAPQ)
{
    const int tid  = threadIdx.x;
    const int w    = tid >> 6, lane = tid & 63;

    __shared__ unsigned long long s_bits[8];
    __shared__ float s_max[16];
    __shared__ float s_tau;
    __shared__ int   s_cnt;
    __shared__ float s_cv[CAPQ];
    __shared__ int   s_ci[CAPQ];

    // ---- classify all 512 rows (thread t -> row t), ballot into LDS ----
    bool validp = false;
    if (tid < ROWS) {
        const int2 mk = ((const int2*)mask)[tid];
        validp = (mk.x + mk.y) == NGRAM;
    }
    const unsigned long long bm = __ballot(validp);
    if (w < 8 && lane == 0) s_bits[w] = bm;
    if (tid == 0) s_cnt = 0;
    __syncthreads();

    int nv = 0;
    #pragma unroll
    for (int i = 0; i < 8; ++i) nv += __popcll(s_bits[i]);
    int k = 1;
    if (nv > 0) {
        const int q = ROWS / nv;
        k = (q >= 8) ? 8 : (q >= 4) ? 4 : (q >= 2) ? 2 : 1;
    }
    if (blockIdx.x == 0 && tid == 0) meta[0] = k;
    const int b = blockIdx.x;
    if (b >= nv * k) return;

    // ---- map b -> (r = vidx-th valid row, slice) ----
    const int vidx  = b / k;
    const int slice = b - vidx * k;
    int r = 0, cnt = 0;
    for (int i = 0; i < 8; ++i) {
        const unsigned long long x = s_bits[i];
        const int c = __popcll(x);
        if (cnt + c > vidx) {
            unsigned long long y = x;
            for (int need = vidx - cnt; need > 0; --need) y &= y - 1;
            r = i * 64 + (__ffsll(y) - 1);
            break;
        }
        cnt += c;
    }

    const size_t rowoff = (size_t)r * VOCAB;
    const float* row = lprobs + rowoff;
    const int segs = SEG / k;
    const int A    = slice * segs * SEGLEN;
    const int Bv   = min(A + segs * SEGLEN, VOCAB);
    const int L    = Bv - A;
    const int subL = (L + 15) >> 4;     // 16 sub-segments, all nonempty

    const int start = A + w * subL;
    const int end   = min(start + subL, Bv);

    // ---- pass 1: sub-segment max; straight-line guarded loads (ILP) ----
    float m = -INFINITY;
    const int mis = (int)((rowoff + start) & 3);
    int pre = (4 - mis) & 3;
    if (pre > end - start) pre = end - start;
    if (lane < pre) m = row[start + lane];
    const int vstart = start + pre;
    const int n4 = (end > vstart) ? ((end - vstart) >> 2) : 0;
    const float4* vrow = (const float4*)(row + vstart);

    float a0 = -INFINITY, a1 = -INFINITY, a2 = -INFINITY, a3 = -INFINITY;
    int jj = lane;
    for (; jj + 192 < n4; jj += 256) {
        a0 = fmaxf(a0, max4(vrow[jj]));
        a1 = fmaxf(a1, max4(vrow[jj + 64]));
        a2 = fmaxf(a2, max4(vrow[jj + 128]));
        a3 = fmaxf(a3, max4(vrow[jj + 192]));
    }
    for (; jj < n4; jj += 64) a0 = fmaxf(a0, max4(vrow[jj]));
    m = fmaxf(m, fmaxf(fmaxf(a0, a1), fmaxf(a2, a3)));
    const int tstart = vstart + 4 * n4;
    if (tstart + lane < end) m = fmaxf(m, row[tstart + lane]);

    #pragma unroll
    for (int off = 32; off > 0; off >>= 1) m = fmaxf(m, __shfl_xor(m, off));
    if (lane == 0) s_max[w] = m;
    __syncthreads();

    // ---- tau = 8th largest (lex) of the 16 sub-maxima: >=8 elems >= tau ----
    if (w == 0) {
        const float mym = (lane < 16) ? s_max[lane] : -INFINITY;
        int rank = 0;
        #pragma unroll
        for (int i = 0; i < 16; ++i) {
            const float om = __shfl(mym, i);
            rank += better(om, i, mym, lane) ? 1 : 0;
        }
        if (lane < 16 && rank == 7) s_tau = mym;    // ranks are a permutation
    }
    __syncthreads();
    const float tau = s_tau;

    // ---- pass 2: rescan only sub-segments with max >= tau (exactly 8) ----
    if (s_max[w] >= tau) {
        if (lane < pre) {
            const float v = row[start + lane];
            if (v >= tau) {
                const int p = atomicAdd(&s_cnt, 1);
                if (p < CAPQ) { s_cv[p] = v; s_ci[p] = start + lane; }
            }
        }
        for (int j2 = lane; j2 < n4; j2 += 64) {
            const float4 v = vrow[j2];
            if (max4(v) >= tau) {
                const int base = vstart + 4 * j2;
                #pragma unroll
                for (int e = 0; e < 4; ++e) {
                    const float ve = (e == 0) ? v.x : (e == 1) ? v.y
                                   : (e == 2) ? v.z : v.w;
                    if (ve >= tau) {
                        const int p = atomicAdd(&s_cnt, 1);
                        if (p < CAPQ) { s_cv[p] = ve; s_ci[p] = base + e; }
                    }
                }
            }
        }
        if (tstart + lane < end) {
            const float v = row[tstart + lane];
            if (v >= tau) {
                const int p = atomicAdd(&s_cnt, 1);
                if (p < CAPQ) { s_cv[p] = v; s_ci[p] = tstart + lane; }
            }
        }
    }
    __syncthreads();

    // ---- emit ----
    const int ccnt = min(s_cnt, CAPQ);
    const int slot = r * MAXK + slice;
    if (tid == 0) wscnt[slot] = ccnt;
    for (int c = tid; c < ccnt; c += 1024) {
        wscv[(size_t)slot * CAPQ + c] = s_cv[c];
        wsci[(size_t)slot * CAPQ + c] = s_ci[c];
    }
}

// ---- K2: per-batch sequential group chain on candidates --------------------
__global__ __launch_bounds__(64) void dbs_final(
    const float* __restrict__ scores,   // (64,8,128)
    const float* __restrict__ overlap,  // (64,4,4)
    const int*   __restrict__ obi,      // (64,)
    const int*   __restrict__ lastn,    // (64,8,1)
    const int*   __restrict__ mask,     // (64,8,2)
    const int*   __restrict__ stepp,    // (1,)
    const int*   __restrict__ meta,
    const int*   __restrict__ wscnt,
    const float* __restrict__ wscv,
    const int*   __restrict__ wsci,
    float*       __restrict__ out)      // 2560 floats
{
    const int b   = blockIdx.x;
    const int tid = threadIdx.x;
    const int step = stepp[0];
    const int ob   = obi[b];

    __shared__ float s_sc[BEAM];
    __shared__ int   s_valid[BEAM];
    __shared__ int   s_k;
    __shared__ float s_pen[(NG-1)*KC];
    __shared__ int   s_penidx[(NG-1)*KC];
    __shared__ float s_selv[NG][KC];
    __shared__ int   s_seli[NG][KC];
    __shared__ int   s_selm[NG][KC];

    if (tid < BEAM) {
        const int* mk = mask + ((size_t)b * BEAM + tid) * NGRAM;
        s_valid[tid] = (mk[0] + mk[1]) == NGRAM;
        s_sc[tid]    = scores[((size_t)b * BEAM + tid) * TLEN + (step - 1)];
    }
    if (tid == 0) s_k = meta[0];
    __syncthreads();
    const int k = s_k;

    for (int g = 0; g < NG; ++g) {
        if (tid == 0) {
            for (int j = 0; j < g; ++j) {
                const float pen = 1.0f + overlap[((size_t)ob * NG + g) * NG + j];
                s_penidx[j*KC + 0] = s_seli[j][0]; s_pen[j*KC + 0] = pen;
                s_penidx[j*KC + 1] = s_seli[j][1]; s_pen[j*KC + 1] = pen;
            }
        }
        __syncthreads();

        const int np = KC * g;            // block-uniform
        Top2 t; t2_init(t);
        for (int m = 0; m < MB; ++m) {
            const int beam = m * NG + g;
            if (s_valid[beam]) {          // block-uniform branch
                const int r = b * BEAM + beam;
                for (int qq = 0; qq < k; ++qq) {
                    const int slot = r * MAXK + qq;
                    const int n = wscnt[slot];
                    for (int c = tid; c < n; c += 64) {
                        const float v   = wscv[(size_t)slot * CAPQ + c];
                        const int   idx = wsci[(size_t)slot * CAPQ + c];
                        float dv = 0.0f;
                        #pragma unroll
                        for (int p = 0; p < (NG-1)*KC; ++p)
                            if (p < np && s_penidx[p] == idx) dv += s_pen[p];
                        t2_push(t, v - 0.5f * dv + s_sc[beam], m * VOCAB + idx);
                    }
                }
            } else if (tid < KC) {
                // invalid row: constant sc -> best two flat idx m*V, m*V+1
                t2_push(t, s_sc[beam], m * VOCAB + tid);
            }
        }

        #pragma unroll
        for (int off = 32; off > 0; off >>= 1) {
            Top2 o;
            o.v1 = __shfl_down(t.v1, off); o.i1 = __shfl_down(t.i1, off);
            o.v2 = __shfl_down(t.v2, off); o.i2 = __shfl_down(t.i2, off);
            t2_merge(t, o);
        }
        if (tid == 0) {
            s_selv[g][0] = t.v1; s_seli[g][0] = t.i1 % VOCAB; s_selm[g][0] = t.i1 / VOCAB;
            s_selv[g][1] = t.v2; s_seli[g][1] = t.i2 % VOCAB; s_selm[g][1] = t.i2 / VOCAB;
        }
        __syncthreads();
    }

    // ---- outputs: scores[0,512) indices[512,1024) beams[1024,1536) overlap[1536,2560)
    if (tid < KC * NG) {                  // i = m*NG + g
        const int i = tid;
        const int m = i / NG, g = i % NG;
        out[(size_t)b * BEAM + i]        = s_selv[g][m];
        out[512 + (size_t)b * BEAM + i]  = (float)s_seli[g][m];
        out[1024 + (size_t)b * BEAM + i] = (float)(s_selm[g][m] * NG + g);
    }
    if (tid >= 16 && tid < 16 + NG * NG) {
        const int q  = tid - 16;
        const int g1 = q / NG, g2 = q % NG;
        int ov = 0;
        for (int m = 0; m < MB; ++m) {
            const int i1 = m * NG + g1, i2 = m * NG + g2;
            const int p1a = lastn[(size_t)b * BEAM + i1];
            const int p2a = lastn[(size_t)b * BEAM + i2];
            const int p1b = s_seli[g1][m];
            const int p2b = s_seli[g2][m];
            const int* mk1 = mask + ((size_t)b * BEAM + i1) * NGRAM;
            const int* mk2 = mask + ((size_t)b * BEAM + i2) * NGRAM;
            const bool e0 = (p1a == p2a) && (mk1[0] != 0) && (mk2[0] != 0);
            const bool e1 = (p1b == p2b) && (mk1[1] != 0) && (mk2[1] != 0);
            ov += (e0 && e1) ? 1 : 0;
        }
        out[1536 + (size_t)ob * (NG * NG) + q] =
            (overlap[(size_t)ob * (NG * NG) + q] + (float)ov) * 0.5f;
    }
}

extern "C" void kernel_launch(void* const* d_in, const int* in_sizes, int n_in,
                              void* d_out, int out_size, void* d_ws, size_t ws_size,
                              hipStream_t stream) {
    const float* lprobs  = (const float*)d_in[0];
    const float* scores  = (const float*)d_in[1];
    const float* overlap = (const float*)d_in[2];
    const int*   obi     = (const int*)d_in[3];
    const int*   lastn   = (const int*)d_in[4];
    const int*   mask    = (const int*)d_in[5];
    const int*   stepp   = (const int*)d_in[6];
    float*       out     = (float*)d_out;

    // ws: meta(16 i32) | wscnt(512*MAXK i32) | wscv | wsci
    int*   meta  = (int*)d_ws;
    int*   wscnt = (int*)((char*)d_ws + 64);
    float* wscv  = (float*)((char*)d_ws + 64 + (size_t)ROWS * MAXK * 4);
    int*   wsci  = (int*)((char*)d_ws + 64 + (size_t)ROWS * MAXK * 4
                          + (size_t)ROWS * MAXK * CAPQ * 4);

    dbs_candidates<<<ROWS, 1024, 0, stream>>>(lprobs, mask, meta, wscnt, wscv, wsci);
    dbs_final     <<<BSZ, 64, 0, stream>>>(scores, overlap, obi, lastn, mask, stepp,
                                           meta, wscnt, wscv, wsci, out);
}